// Round 16
// baseline (80.563 us; speedup 1.0000x reference)
//
#include <hip/hip_runtime.h>

#define C_NUM    256
#define KCODES   4096
#define THREADS  512
#define CHUNK    1024
#define NCHUNK   4
#define NTILES   (CHUNK / 16)     // 64 tiles of 16 codes per chunk
#define AROW     80               // bytes per code row in LDS (64 payload + 16 pad -> conflict-free)
#define MARGIN   0.125f           // certainty margin >> worst-case approx+trunc error (~0.03)

// LDS layout (bytes)
#define OFF_A    0
#define OFF_XS   (CHUNK * AROW)          // 81920 : float xs[128][8]
#define OFF_BEST (OFF_XS + 4096)         // 86016 : int best[128]
#define OFF_UL   (OFF_BEST + 512)        // 86528 : int ulist[128]
#define OFF_NU   (OFF_UL + 512)          // 87040 : int nu
#define SMEM_SZ  (OFF_NU + 16)           // 87056

typedef short  bf16x8 __attribute__((ext_vector_type(8)));
typedef float  f32x4  __attribute__((ext_vector_type(4)));
typedef float  v4f    __attribute__((ext_vector_type(4)));

// f32 -> bf16 (round-to-nearest-even), bits in low 16. Portable, branchless.
__device__ __forceinline__ unsigned short bf16rn(float f) {
    unsigned u = __float_as_uint(f);
    u += 0x7FFFu + ((u >> 16) & 1u);
    return (unsigned short)(u >> 16);
}
__device__ __forceinline__ float bf16tof(unsigned short h) {
    return __uint_as_float(((unsigned)h) << 16);
}

__global__ __launch_bounds__(THREADS, 2)
void dkvb_kernel(const float* __restrict__ emb,
                 const float* __restrict__ keys,
                 const float* __restrict__ values,
                 float* __restrict__ out) {
    extern __shared__ unsigned char sm[];
    float (*xs)[8] = (float(*)[8])(sm + OFF_XS);
    int* best  = (int*)(sm + OFF_BEST);
    int* ulist = (int*)(sm + OFF_UL);
    int* nu    = (int*)(sm + OFF_NU);

    const int c    = blockIdx.x;          // one codebook per block
    const int tid  = threadIdx.x;
    const int wave = tid >> 6;
    const int lane = tid & 63;
    const int col  = lane & 15;           // B col / D col
    const int g    = lane >> 4;           // k-group (0..3) / D row-group
    const int arow = lane & 15;           // A row within tile

    const v4f* kb4 = (const v4f*)(keys + (size_t)c * KCODES * 8);

    if (tid == 0) *nu = 0;

    // ---- stage x for all 128 tuples: xs[t][j] = emb[(t>>4)*32768 + c*128 + j*16 + (t&15)] ----
    #pragma unroll
    for (int r = 0; r < 2; ++r) {
        const int e = tid + r * THREADS;
        const int t = e >> 3, j = e & 7;
        xs[t][j] = emb[(size_t)(t >> 4) * 32768 + c * 128 + j * 16 + (t & 15)];
    }
    __syncthreads();

    // ---- build this wave's fixed B-frag (16 tuples = tuple-tile `wave`) ----
    // B k-slots: [0-7: xh | 8-15: xh | 16-23: xl | 24:1 25:1 26:x2h 27:x2l 28-31:0]
    bf16x8 bfrag;
    {
        const int t = wave * 16 + col;
        float xv[8];
        #pragma unroll
        for (int j = 0; j < 8; ++j) xv[j] = xs[t][j];
        float x2 = xv[0] * xv[0];
        #pragma unroll
        for (int j = 1; j < 8; ++j) x2 = fmaf(xv[j], xv[j], x2);
        bf16x8 fxh, fxl, fct;
        #pragma unroll
        for (int j = 0; j < 8; ++j) {
            const unsigned short h = bf16rn(xv[j]);
            fxh[j] = (short)h;
            fxl[j] = (short)bf16rn(xv[j] - bf16tof(h));
        }
        const unsigned short x2h = bf16rn(x2);
        const unsigned short x2l = bf16rn(x2 - bf16tof(x2h));
        fct[0] = (short)0x3F80; fct[1] = (short)0x3F80;   // 1.0bf, 1.0bf (k2h,k2l slots)
        fct[2] = (short)x2h;    fct[3] = (short)x2l;
        fct[4] = 0; fct[5] = 0; fct[6] = 0; fct[7] = 0;
        bfrag = (g < 2) ? fxh : ((g == 2) ? fxl : fct);
    }

    const f32x4 zeroC = {0.f, 0.f, 0.f, 0.f};
    unsigned m1 = 0xFFFFFFFFu, m2 = 0xFFFFFFFFu;
    const int rowbase = g * 4;            // D rows owned by this lane

    // ---- 4 chunks: convert 1024 codes -> LDS A-frags, then all 8 waves scan ----
    for (int ph = 0; ph < NCHUNK; ++ph) {
        const int cbase = ph * CHUNK;

        // convert: 2 codes/thread. A k-slots per code:
        // [0-7: -2kh | 8-15: -2kl | 16-23: -2kh | 24:k2h 25:k2l 26:1 27:1 28-31:0]
        #pragma unroll
        for (int r = 0; r < 2; ++r) {
            const int ci   = r * THREADS + tid;       // 0..1023
            const int code = cbase + ci;
            const v4f p0 = kb4[code * 2];
            const v4f p1 = kb4[code * 2 + 1];
            float kk[8] = {p0.x, p0.y, p0.z, p0.w, p1.x, p1.y, p1.z, p1.w};
            float k2 = kk[0] * kk[0];
            #pragma unroll
            for (int j = 1; j < 8; ++j) k2 = fmaf(kk[j], kk[j], k2);
            unsigned short th[8], tl[8];
            #pragma unroll
            for (int j = 0; j < 8; ++j) {
                const float tt = -2.0f * kk[j];
                th[j] = bf16rn(tt);
                tl[j] = bf16rn(tt - bf16tof(th[j]));
            }
            const unsigned short k2h = bf16rn(k2);
            const unsigned short k2l = bf16rn(k2 - bf16tof(k2h));
            unsigned w[16];
            #pragma unroll
            for (int i = 0; i < 4; ++i) w[i]     = (unsigned)th[2*i] | ((unsigned)th[2*i+1] << 16);
            #pragma unroll
            for (int i = 0; i < 4; ++i) w[4 + i] = (unsigned)tl[2*i] | ((unsigned)tl[2*i+1] << 16);
            #pragma unroll
            for (int i = 0; i < 4; ++i) w[8 + i] = w[i];
            w[12] = (unsigned)k2h | ((unsigned)k2l << 16);
            w[13] = 0x3F803F80u;
            w[14] = 0u; w[15] = 0u;
            uint4* dst = (uint4*)(sm + OFF_A + (size_t)ci * AROW);
            dst[0] = make_uint4(w[0],  w[1],  w[2],  w[3]);
            dst[1] = make_uint4(w[4],  w[5],  w[6],  w[7]);
            dst[2] = make_uint4(w[8],  w[9],  w[10], w[11]);
            dst[3] = make_uint4(w[12], w[13], w[14], w[15]);
        }
        __syncthreads();

        // scan: each wave does 64 MFMAs over this chunk for its tuple-tile
        const unsigned char* abase = sm + OFF_A + (size_t)arow * AROW + (size_t)g * 16;
        for (int tile = 0; tile < NTILES; ++tile) {
            const bf16x8 afrag = *(const bf16x8*)(abase + tile * (16 * AROW));
            const f32x4 D = __builtin_amdgcn_mfma_f32_16x16x32_bf16(afrag, bfrag, zeroC, 0, 0, 0);
            const int codeb = cbase + tile * 16 + rowbase;
            #pragma unroll
            for (int r2 = 0; r2 < 4; ++r2) {
                const unsigned key = (__float_as_uint(D[r2]) & 0xFFFFF000u) | (unsigned)(codeb + r2);
                const unsigned hi = (m1 > key) ? m1 : key;
                m1 = (m1 < key) ? m1 : key;
                m2 = (m2 < hi) ? m2 : hi;
            }
        }
        __syncthreads();   // scan done before next chunk's convert overwrites A
    }

    // ---- reduce (m1,m2) across the 4 row-groups sharing each column ----
    #pragma unroll
    for (int sh = 16; sh <= 32; sh <<= 1) {
        const unsigned o1 = (unsigned)__shfl_xor((int)m1, sh, 64);
        const unsigned o2 = (unsigned)__shfl_xor((int)m2, sh, 64);
        const unsigned hi  = (m1 > o1) ? m1 : o1;
        m1 = (m1 < o1) ? m1 : o1;
        const unsigned mn2 = (m2 < o2) ? m2 : o2;
        m2 = (mn2 < hi) ? mn2 : hi;
    }
    if (lane < 16) {
        const int t = wave * 16 + lane;
        best[t] = (int)(m1 & 0xFFFu);
        const float v1 = __uint_as_float(m1 & 0xFFFFF000u);
        const float v2 = __uint_as_float(m2 & 0xFFFFF000u);
        if (v2 - v1 < MARGIN) {            // not provably separated -> exact rescan
            const int idx = atomicAdd(nu, 1);
            ulist[idx] = t;
        }
    }
    __syncthreads();

    // ---- exact refine (rare): full fp32 scan with R14's proven chain ----
    const int NU = *nu;
    for (int e = wave; e < NU; e += 8) {
        const int t = ulist[e];
        float xp[8];
        #pragma unroll
        for (int j = 0; j < 8; ++j) xp[j] = -2.0f * xs[t][j];
        float bd = 3.4028235e38f;
        int   bi = 0;
        for (int it = 0; it < 64; ++it) {
            const int code = it * 64 + lane;
            const v4f p0 = kb4[code * 2];
            const v4f p1 = kb4[code * 2 + 1];
            float k2 = p0.x * p0.x;
            k2 = fmaf(p0.y, p0.y, k2);
            k2 = fmaf(p0.z, p0.z, k2);
            k2 = fmaf(p0.w, p0.w, k2);
            k2 = fmaf(p1.x, p1.x, k2);
            k2 = fmaf(p1.y, p1.y, k2);
            k2 = fmaf(p1.z, p1.z, k2);
            k2 = fmaf(p1.w, p1.w, k2);
            float d = fmaf(xp[0], p0.x, k2);
            d = fmaf(xp[1], p0.y, d);
            d = fmaf(xp[2], p0.z, d);
            d = fmaf(xp[3], p0.w, d);
            d = fmaf(xp[4], p1.x, d);
            d = fmaf(xp[5], p1.y, d);
            d = fmaf(xp[6], p1.z, d);
            d = fmaf(xp[7], p1.w, d);
            if (d < bd) { bd = d; bi = code; }   // ascending order -> numpy tie-break
        }
        #pragma unroll
        for (int msk = 32; msk >= 1; msk >>= 1) {
            const float od = __shfl_xor(bd, msk, 64);
            const int   oi = __shfl_xor(bi, msk, 64);
            if (od < bd || (od == bd && oi < bi)) { bd = od; bi = oi; }
        }
        if (lane == 0) best[t] = bi;
    }
    __syncthreads();

    // ---- gather values + scatter output ----
    if (tid < 128) {
        const int t = tid;
        const int code = best[t];
        const v4f* vr = (const v4f*)(values + ((size_t)c * KCODES + code) * 8);
        const v4f v0 = vr[0];
        const v4f v1 = vr[1];
        float* op = out + (size_t)(t >> 4) * 32768 + c * 128 + (t & 15);
        op[0]   = v0.x; op[16]  = v0.y; op[32]  = v0.z; op[48]  = v0.w;
        op[64]  = v1.x; op[80]  = v1.y; op[96]  = v1.z; op[112] = v1.w;
    }
}

extern "C" void kernel_launch(void* const* d_in, const int* in_sizes, int n_in,
                              void* d_out, int out_size, void* d_ws, size_t ws_size,
                              hipStream_t stream) {
    const float* emb    = (const float*)d_in[0];
    const float* keys   = (const float*)d_in[1];
    const float* values = (const float*)d_in[2];
    float* out = (float*)d_out;

    hipFuncSetAttribute((const void*)dkvb_kernel,
                        hipFuncAttributeMaxDynamicSharedMemorySize, SMEM_SZ);
    dkvb_kernel<<<C_NUM, THREADS, SMEM_SZ, stream>>>(emb, keys, values, out);
}